// Round 8
// baseline (547.948 us; speedup 1.0000x reference)
//
#include <hip/hip_runtime.h>
#include <hip/hip_bf16.h>
#include <math.h>

// Problem constants
#define BB 4
#define TT 1536
#define CC 1536
#define HH 8
#define DKk 64
#define DVv 192
#define NBASIS 32
#define LREL 3071          // 2T-1
#define MROWS 6144         // B*T

typedef short short8 __attribute__((ext_vector_type(8)));
typedef float floatx4 __attribute__((ext_vector_type(4)));

static __device__ inline short f2bf(float f) {
  __hip_bfloat16 h = __float2bfloat16(f);
  return *reinterpret_cast<short*>(&h);
}

// async global->LDS, 16B per lane; LDS dest = wave-uniform base + lane*16
static __device__ inline void gload_lds16(const __hip_bfloat16* g, __hip_bfloat16* l) {
  __builtin_amdgcn_global_load_lds(
      (const __attribute__((address_space(1))) unsigned int*)g,
      (__attribute__((address_space(3))) unsigned int*)l, 16, 0, 0);
}

// ---------------------------------------------------------------------------
// Stage 0: dtype detection (fp32 vs bf16 input payloads).
// ---------------------------------------------------------------------------
__global__ void detect_kernel(const void* __restrict__ x, int* __restrict__ flag) {
  if (threadIdx.x == 0 && blockIdx.x == 0) {
    const __hip_bfloat16* h = (const __hip_bfloat16*)x;
    int cnt = 0;
    for (int i = 0; i < 64; ++i) {
      float v = fabsf((float)h[2 * i]);
      if (v > 1e-5f && v < 256.0f) cnt++;
    }
    *flag = (cnt >= 32) ? 1 : 0;  // 1 => inputs are bf16
  }
}

__global__ __launch_bounds__(256) void convert_kernel(const void* __restrict__ src,
                                                      float* __restrict__ dst, int n,
                                                      const int* __restrict__ flag) {
  const int i = blockIdx.x * 256 + threadIdx.x;
  if (i >= n) return;
  if (*flag) dst[i] = (float)((const __hip_bfloat16*)src)[i];
  else       dst[i] = ((const float*)src)[i];
}

__global__ __launch_bounds__(256) void convbf_kernel(const void* __restrict__ src,
                                                     __hip_bfloat16* __restrict__ dst, int n,
                                                     const int* __restrict__ flag) {
  const int i = blockIdx.x * 256 + threadIdx.x;
  if (i >= n) return;
  if (*flag) dst[i] = ((const __hip_bfloat16*)src)[i];
  else       dst[i] = __float2bfloat16(((const float*)src)[i]);
}

// ---------------------------------------------------------------------------
// Weight transpose: src [K,N] (fp32/bf16 per flag) -> dst bf16 [N,K]
// ---------------------------------------------------------------------------
__global__ __launch_bounds__(256) void wt_kernel(const void* __restrict__ src,
                                                 __hip_bfloat16* __restrict__ dst,
                                                 int K, int N, const int* __restrict__ flag) {
  __shared__ __hip_bfloat16 tile[64][68];
  const int tid = threadIdx.x;
  const int k0 = blockIdx.y * 64, n0 = blockIdx.x * 64;
  const bool bf = (*flag != 0);
  {
    const int r = tid >> 2, c0 = (tid & 3) * 16;
    if (bf) {
      const __hip_bfloat16* sp = (const __hip_bfloat16*)src + (size_t)(k0 + r) * N + n0 + c0;
#pragma unroll
      for (int u = 0; u < 16; ++u) tile[r][c0 + u] = sp[u];
    } else {
      const float* sp = (const float*)src + (size_t)(k0 + r) * N + n0 + c0;
#pragma unroll
      for (int u = 0; u < 16; ++u) tile[r][c0 + u] = __float2bfloat16(sp[u]);
    }
  }
  __syncthreads();
  {
    const int nr = tid >> 2, c0 = (tid & 3) * 16;
    __hip_bfloat16* dp = dst + (size_t)(n0 + nr) * K + k0 + c0;
#pragma unroll
    for (int u = 0; u < 16; ++u) dp[u] = tile[c0 + u][nr];
  }
}

// ---------------------------------------------------------------------------
// Stage 1: gamma-basis max over pos (fp64). One block per basis j.
// ---------------------------------------------------------------------------
__global__ void gmax_kernel(double* __restrict__ gmax) {
  const int j = blockIdx.x;
  const double mean = 48.0 + 1488.0 * (double)j / 31.0;
  const double conc = (mean / 24.0) * (mean / 24.0);
  const double rate = mean / 576.0;
  const double log_norm = lgamma(conc) - conc * log(rate);
  double mx = 1e-8;
  for (int pos = 1 + threadIdx.x; pos <= 1535; pos += 256) {
    double p = exp((conc - 1.0) * log((double)pos) - rate * (double)pos - log_norm) + 1e-8;
    mx = fmax(mx, p);
  }
  __shared__ double red[256];
  red[threadIdx.x] = mx;
  __syncthreads();
  for (int s = 128; s > 0; s >>= 1) {
    if (threadIdx.x < s) red[threadIdx.x] = fmax(red[threadIdx.x], red[threadIdx.x + s]);
    __syncthreads();
  }
  if (threadIdx.x == 0) gmax[j] = red[0];
}

// ---------------------------------------------------------------------------
// Stage 2: pe[l, f], fp64 math, fp32 store.
// ---------------------------------------------------------------------------
__global__ void pe_kernel(float* __restrict__ pe, const double* __restrict__ gmax) {
  const int l = blockIdx.x;
  const int f = threadIdx.x;  // 0..191
  const int dist = l - (TT - 1);
  const int pos = dist < 0 ? -dist : dist;
  const int base = f % 96;
  const int cls = base / 32;
  const int j = base % 32;
  double v;
  if (cls == 0) {
    const double max_range = log(1536.0) / log(2.0);
    const double e = 3.0 + (max_range - 3.0) * (double)j / 31.0;
    const double hl = exp2(e);
    v = exp2(-(double)pos / hl);
  } else if (cls == 1) {
    const double width = exp2((double)(j + 1)) - 1.0;
    v = (width > (double)pos) ? 1.0 : 0.0;
  } else {
    const double mean = 48.0 + 1488.0 * (double)j / 31.0;
    const double conc = (mean / 24.0) * (mean / 24.0);
    const double rate = mean / 576.0;
    double p;
    if (pos == 0) {
      p = 1e-8;
    } else {
      const double log_norm = lgamma(conc) - conc * log(rate);
      p = exp((conc - 1.0) * log((double)pos) - rate * (double)pos - log_norm) + 1e-8;
    }
    v = p / gmax[j];
  }
  float out = (float)v;
  if (f >= 96) {
    float sgn = (dist > 0) ? 1.f : (dist < 0 ? -1.f : 0.f);
    out *= sgn;
  }
  pe[(size_t)l * 192 + f] = out;
}

// ---------------------------------------------------------------------------
// Stage 3: rKl[h][l][d] (bf16) = sum_f pe[l,f] * W_rel_k[f, h*64+d]
// ---------------------------------------------------------------------------
__global__ __launch_bounds__(512) void relk_kernel(const float* __restrict__ pe,
                                                   const float* __restrict__ Wrk,
                                                   __hip_bfloat16* __restrict__ rKl) {
  __shared__ float pes[8][192];
  const int l0 = blockIdx.x * 8;
  const int nrows = (LREL - l0) < 8 ? (LREL - l0) : 8;
  const int tid = threadIdx.x;
  for (int idx = tid; idx < nrows * 192; idx += 512) {
    int r = idx / 192, f = idx % 192;
    pes[r][f] = pe[(size_t)(l0 + r) * 192 + f];
  }
  __syncthreads();
  float acc[8] = {0.f, 0.f, 0.f, 0.f, 0.f, 0.f, 0.f, 0.f};
  for (int f = 0; f < 192; ++f) {
    float w = Wrk[(size_t)f * 512 + tid];
#pragma unroll
    for (int r = 0; r < 8; ++r) acc[r] += pes[r][f] * w;
  }
  const int h = tid >> 6, d = tid & 63;
  for (int r = 0; r < nrows; ++r)
    rKl[((size_t)h * LREL + (l0 + r)) * 64 + d] = __float2bfloat16(acc[r]);
}

// ---------------------------------------------------------------------------
// bf16 MFMA GEMM, BK=64, XOR granule swizzle, XCD-bijective block swizzle
// (m204 formula; grids here always have nwg % 8 == 0).
//   C[M,N] = A[M,K] @ Bt[N,K]^T ; 128x128 tile, 4 waves.
// MODE 2: d_out per flag (+bias); MODE 3: fused QKV (N=2560):
//   cols<512 -> fp32 Cout; 512..1023 -> bf16 Cout2; >=1024 -> bf16 Cout3.
// ---------------------------------------------------------------------------
template <int MODE, bool BIAS>
__global__ __launch_bounds__(256) void gemm_mfma(const __hip_bfloat16* __restrict__ A,
                                                 const __hip_bfloat16* __restrict__ Bt,
                                                 void* __restrict__ Cout,
                                                 void* __restrict__ Cout2,
                                                 void* __restrict__ Cout3,
                                                 const float* __restrict__ bias,
                                                 int M, int N, int K,
                                                 const int* __restrict__ flag) {
  __shared__ __align__(16) __hip_bfloat16 As[128 * 64];
  __shared__ __align__(16) __hip_bfloat16 Bs[128 * 64];
  const int tid = threadIdx.x;
  const int w = tid >> 6, lane = tid & 63;
  const int quad = lane >> 4, l16 = lane & 15;
  const int wm = w >> 1, wn = w & 1;
  // XCD-bijective swizzle: o = (id%8)*(nwg/8) + id/8 (bijective since nwg%8==0)
  const int gx = gridDim.x;
  const int nwg = gx * gridDim.y;
  const int id = blockIdx.y * gx + blockIdx.x;
  const int o = (id & 7) * (nwg >> 3) + (id >> 3);
  const int row0 = (o / gx) * 128, col0 = (o % gx) * 128;

  const floatx4 vzero = {0.f, 0.f, 0.f, 0.f};
  floatx4 acc[4][4];
#pragma unroll
  for (int i = 0; i < 4; ++i)
#pragma unroll
    for (int j = 0; j < 4; ++j) acc[i][j] = vzero;

  // staging: each wave stages 32 rows of A and B (4 x 1KB chunks each).
  // chunk covers 8 rows; sr = row within chunk; source granule pre-swizzled.
  const int sr = lane >> 3;              // 0..7
  const int sg = (lane & 7) ^ sr;        // swizzled 8-elem granule
  const __hip_bfloat16* ag = A + (size_t)(row0 + w * 32 + sr) * K + sg * 8;
  const __hip_bfloat16* bg = Bt + (size_t)(col0 + w * 32 + sr) * K + sg * 8;
  __hip_bfloat16* as_ = As + w * 32 * 64;
  __hip_bfloat16* bs_ = Bs + w * 32 * 64;

  for (int k0 = 0; k0 < K; k0 += 64) {
    __syncthreads();
#pragma unroll
    for (int i = 0; i < 4; ++i) {
      gload_lds16(ag + (size_t)(i * 8) * K + k0, as_ + i * 8 * 64);
      gload_lds16(bg + (size_t)(i * 8) * K + k0, bs_ + i * 8 * 64);
    }
    __syncthreads();
#pragma unroll
    for (int ks = 0; ks < 2; ++ks) {
      const int xr = (((ks * 4 + quad) ^ (l16 & 7)) << 3);
      short8 aF[4], bF[4];
#pragma unroll
      for (int mt = 0; mt < 4; ++mt)
        aF[mt] = *(const short8*)(As + (wm * 64 + mt * 16 + l16) * 64 + xr);
#pragma unroll
      for (int nt = 0; nt < 4; ++nt)
        bF[nt] = *(const short8*)(Bs + (wn * 64 + nt * 16 + l16) * 64 + xr);
#pragma unroll
      for (int mt = 0; mt < 4; ++mt)
#pragma unroll
        for (int nt = 0; nt < 4; ++nt)
          acc[mt][nt] = __builtin_amdgcn_mfma_f32_16x16x32_bf16(aF[mt], bF[nt], acc[mt][nt], 0, 0, 0);
    }
  }

  const bool obf = (MODE == 2) ? (*flag != 0) : false;
#pragma unroll
  for (int mt = 0; mt < 4; ++mt) {
#pragma unroll
    for (int r = 0; r < 4; ++r) {
      const int row = row0 + wm * 64 + mt * 16 + quad * 4 + r;
#pragma unroll
      for (int nt = 0; nt < 4; ++nt) {
        const int col = col0 + wn * 64 + nt * 16 + l16;
        float v = acc[mt][nt][r];
        if (BIAS) v += bias[col];
        if (MODE == 0) {
          ((float*)Cout)[(size_t)row * N + col] = v;
        } else if (MODE == 1) {
          ((__hip_bfloat16*)Cout)[(size_t)row * N + col] = __float2bfloat16(v);
        } else if (MODE == 2) {
          if (obf) ((__hip_bfloat16*)Cout)[(size_t)row * N + col] = __float2bfloat16(v);
          else     ((float*)Cout)[(size_t)row * N + col] = v;
        } else {  // MODE 3: Q fp32 | K bf16 | V bf16
          if (col < 512)
            ((float*)Cout)[(size_t)row * 512 + col] = v;
          else if (col < 1024)
            ((__hip_bfloat16*)Cout2)[(size_t)row * 512 + (col - 512)] = __float2bfloat16(v);
          else
            ((__hip_bfloat16*)Cout3)[(size_t)row * 1536 + (col - 1024)] = __float2bfloat16(v);
        }
      }
    }
  }
}

// ---------------------------------------------------------------------------
// K fragment pack: Kbf [b*T+t][h*64+d] -> Kfrag words [bh][ktile(96)][ks(2)][lane][8]
// ---------------------------------------------------------------------------
__global__ __launch_bounds__(256) void kfrag_kernel(const __hip_bfloat16* __restrict__ Kbf,
                                                    __hip_bfloat16* __restrict__ Kfrag) {
  const int widx = blockIdx.x * 256 + threadIdx.x;   // < 32*96*2*64 = 393216
  const int lane = widx & 63;
  const int ks = (widx >> 6) & 1;
  const int kt = (widx >> 7) % 96;
  const int bh = (widx >> 7) / 96;
  const int b = bh >> 3, h = bh & 7;
  const __hip_bfloat16* src = Kbf + ((size_t)(b * TT + kt * 16 + (lane & 15))) * 512
                              + h * 64 + ks * 32 + (lane >> 4) * 8;
  *(uint4*)(Kfrag + (size_t)widx * 8) = *(const uint4*)src;
}

// ---------------------------------------------------------------------------
// rK fragment pack: rKl [h*3071+l][64] -> rKfrag words [h][lt(192)][ks(2)][lane][8]
// ---------------------------------------------------------------------------
__global__ __launch_bounds__(256) void rkfrag_kernel(const __hip_bfloat16* __restrict__ rKl,
                                                     __hip_bfloat16* __restrict__ rKfrag) {
  const int widx = blockIdx.x * 256 + threadIdx.x;   // < 8*192*2*64 = 196608
  const int lane = widx & 63;
  const int ks = (widx >> 6) & 1;
  const int lt = (widx >> 7) % 192;
  const int h = (widx >> 7) / 192;
  int l = lt * 16 + (lane & 15);
  if (l > 3070) l = 3070;   // row l=3071 is fetched but never consumed (j<=126)
  const __hip_bfloat16* src = rKl + ((size_t)h * LREL + l) * 64 + ks * 32 + (lane >> 4) * 8;
  *(uint4*)(rKfrag + (size_t)widx * 8) = *(const uint4*)src;
}

// ---------------------------------------------------------------------------
// V fragment pack: Vbf [b*T+t][h*192+v] -> Vfrag words [bh][kb(24)][vt(12)][ks(2)][lane][8]
// ---------------------------------------------------------------------------
__global__ __launch_bounds__(256) void vfrag_kernel(const __hip_bfloat16* __restrict__ Vbf,
                                                    __hip_bfloat16* __restrict__ Vfrag) {
  int bid = blockIdx.x;            // 4*8*24*3 = 2304
  int vt3 = bid % 3; int kb = (bid / 3) % 24; int h = (bid / 72) & 7; int b = bid / 576;
  const int bh = b * 8 + h;
  __shared__ __hip_bfloat16 tile[64][72];   // [t][v]
  const int tid = threadIdx.x;
  {
    int r = tid >> 2, c0 = (tid & 3) * 16;   // r: t-row, c: v-col
    const __hip_bfloat16* src = Vbf + (size_t)(b * TT + kb * 64 + r) * 1536 + h * 192 + vt3 * 64 + c0;
#pragma unroll
    for (int u = 0; u < 16; ++u) tile[r][c0 + u] = src[u];
  }
  __syncthreads();
#pragma unroll
  for (int u = 0; u < 2; ++u) {
    const int w512 = u * 256 + tid;          // 0..511 words of this tile
    const int vtl = w512 >> 7;               // 0..3 (local v-tile)
    const int ks = (w512 >> 6) & 1;
    const int ln = w512 & 63;
    const int qd = ln >> 4, s16 = ln & 15;
    union { uint4 u4; unsigned short us[8]; } pk;
#pragma unroll
    for (int j = 0; j < 8; ++j)
      pk.us[j] = *(const unsigned short*)&tile[ks * 32 + qd * 8 + j][vtl * 16 + s16];
    __hip_bfloat16* dst = Vfrag +
        (((size_t)(bh * 24 + kb) * 12 + vt3 * 4 + vtl) * 2 + ks) * 512 + (size_t)ln * 8;
    *(uint4*)dst = pk.u4;
  }
}

// ---------------------------------------------------------------------------
// MFMA flash attention — 2-barrier pipelined skeleton (round-7 proven) +
// IN-REGISTER shuffle diagonal gather (Rbuf eliminated):
//   target S[kt][r] needs compacted col cj = kt*16 + l16 + 15 - q4r
//   (q4r=quad*4+r). Since cj>>4 = kt + (l16>q4r) and cj&15 = (l16-q4r-1)&15,
//   the value is R[kt + (l16>q4r)][r] shuffled from lane (lane&48)+(cj&15)
//   (same quad, same element r; all register indices compile-time).
//   Replaces 20 LDS stores + 16 conflicted scalar loads with 32 bpermutes;
//   LDS drops 45056 -> 34304 B  =>  4 blocks/CU (launch_bounds(256,4)).
// ---------------------------------------------------------------------------
__global__ __launch_bounds__(256, 4) void attn_frag(
    const float* __restrict__ tmpQ,                 // [b*T+t][512] fp32
    const float* __restrict__ rwb,                  // [512]
    const float* __restrict__ rrb,                  // [512]
    const __hip_bfloat16* __restrict__ Kfrag,       // [bh][96][2][64][8]
    const __hip_bfloat16* __restrict__ rKfrag,      // [h][192][2][64][8]
    const __hip_bfloat16* __restrict__ Vfrag,       // [bh][24][12][2][64][8]
    __hip_bfloat16* __restrict__ O)                 // [b*T+q][1536] bf16
{
  const int tid = threadIdx.x;
  const int w = tid >> 6, lane = tid & 63;
  const int quad = lane >> 4, l16 = lane & 15;
  const int le8 = lane * 8;   // elem offset of this lane within a fragment word
  // XCD-bijective swizzle (768 % 8 == 0): 96 consecutive logical blocks/XCD.
  const int o = (blockIdx.x & 7) * 96 + (blockIdx.x >> 3);
  const int qt = o % 24;
  const int h = (o / 24) & 7;
  const int b = o / 192;
  const int bh = b * 8 + h;
  const int q0 = qt * 64;

  // LDS (bytes): Klds @0 (8192) | rKlds @8192 (16384) | Ptile @24576 (9216)
  //              alphaS @33792 (256) | lrowS @34048 (256).  Total 34304.
  __shared__ __align__(16) char sm[34304];
  __hip_bfloat16* Klds  = (__hip_bfloat16*)sm;
  __hip_bfloat16* rKlds = (__hip_bfloat16*)(sm + 8192);
  __hip_bfloat16* Ptile = (__hip_bfloat16*)(sm + 24576);
  float* alphaS = (float*)(sm + 33792);
  float* lrowS  = (float*)(sm + 34048);

  // Q fragments (A-layout): lane holds A[m=l16][k=quad*8+j], kstep*32 offset.
  short8 aQw[2], aQr[2];
  {
    const int qrow = q0 + w * 16 + l16;
    const float* qp = tmpQ + (size_t)(b * TT + qrow) * 512 + h * 64;
#pragma unroll
    for (int ks = 0; ks < 2; ++ks) {
#pragma unroll
      for (int j = 0; j < 8; ++j) {
        const int d = ks * 32 + quad * 8 + j;
        const float qv = qp[d] * 0.125f;
        aQw[ks][j] = f2bf(qv + rwb[h * 64 + d]);
        aQr[ks][j] = f2bf(qv + rrb[h * 64 + d]);
      }
    }
  }

  const floatx4 vzero = {0.f, 0.f, 0.f, 0.f};
  floatx4 Oacc[12];   // [qf(4)][vtl(3)] : rows qf*16+quad*4+r, cols (w*3+vtl)*16+l16
#pragma unroll
  for (int i = 0; i < 12; ++i) Oacc[i] = vzero;
  float mrow[4], lrow[4];
#pragma unroll
  for (int r = 0; r < 4; ++r) { mrow[r] = -INFINITY; lrow[r] = 0.f; }

  // staging source pointers: kSrc/rSrc carry the per-lane 16B granule (le8)
  // because gload_lds takes per-lane GLOBAL addresses. vSrc does NOT (plain
  // vector loads add le8 at the read site).
  const __hip_bfloat16* kSrc = Kfrag + (size_t)bh * 98304 + le8;
  const __hip_bfloat16* rSrc = rKfrag + (size_t)h * 196608
                               + (size_t)((1472 - q0) >> 4) * 1024 + le8;
  const __hip_bfloat16* vSrc = Vfrag + (size_t)bh * 294912;

  const int jt0 = 3 - w;   // wave w consumes jt tiles jt0..jt0+4 only

  // K(8 words) + rK(16 words) staged per iter; 6 gload_lds per wave.
  auto stage = [&](int t) {
    const __hip_bfloat16* kIt = kSrc + (size_t)(t * 4) * 1024;
    const __hip_bfloat16* rIt = rSrc + (size_t)(t * 4) * 1024;
    if (w == 0) {
#pragma unroll
      for (int i = 0; i < 6; ++i) gload_lds16(kIt + i * 512, Klds + i * 512);
    } else if (w == 1) {
#pragma unroll
      for (int i = 6; i < 8; ++i) gload_lds16(kIt + i * 512, Klds + i * 512);
#pragma unroll
      for (int i = 0; i < 4; ++i) gload_lds16(rIt + i * 512, rKlds + i * 512);
    } else if (w == 2) {
#pragma unroll
      for (int i = 4; i < 10; ++i) gload_lds16(rIt + i * 512, rKlds + i * 512);
    } else {
#pragma unroll
      for (int i = 10; i < 16; ++i) gload_lds16(rIt + i * 512, rKlds + i * 512);
    }
  };

  stage(0);  // prologue

  for (int t = 0; t < 24; ++t) {
    __syncthreads();  // B2: stage(t) DMA drained+visible; Ptile(t-1) PV reads done

    // V fragments straight into regs (hidden under QK/R MFMAs below)
    short8 vReg[3][2];
    {
      const __hip_bfloat16* vIt = vSrc + (size_t)t * 12288;
#pragma unroll
      for (int vtl = 0; vtl < 3; ++vtl)
#pragma unroll
        for (int ks = 0; ks < 2; ++ks)
          vReg[vtl][ks] = *(const short8*)(vIt + ((w * 3 + vtl) * 2 + ks) * 512 + le8);
    }

    floatx4 S[4], R[5];
#pragma unroll
    for (int i = 0; i < 4; ++i) S[i] = vzero;
#pragma unroll
    for (int i = 0; i < 5; ++i) R[i] = vzero;

    __builtin_amdgcn_s_setprio(1);
#pragma unroll
    for (int kt = 0; kt < 4; ++kt) {
#pragma unroll
      for (int ks = 0; ks < 2; ++ks) {
        short8 bK = *(const short8*)(Klds + (kt * 2 + ks) * 512 + le8);
        S[kt] = __builtin_amdgcn_mfma_f32_16x16x32_bf16(aQw[ks], bK, S[kt], 0, 0, 0);
      }
    }
#pragma unroll
    for (int i = 0; i < 5; ++i) {
      const int jt = jt0 + i;
#pragma unroll
      for (int ks = 0; ks < 2; ++ks) {
        short8 bR = *(const short8*)(rKlds + (jt * 2 + ks) * 512 + le8);
        R[i] = __builtin_amdgcn_mfma_f32_16x16x32_bf16(aQr[ks], bR, R[i], 0, 0, 0);
      }
    }
    __builtin_amdgcn_s_setprio(0);

    // in-register diagonal shift gather (see header comment for derivation)
#pragma unroll
    for (int kt = 0; kt < 4; ++kt) {
#pragma unroll
      for (int r = 0; r < 4; ++r) {
        const int q4r = quad * 4 + r;
        const int srcLane = (lane & 48) + ((l16 - q4r - 1) & 15);
        const float lo = __shfl(R[kt][r], srcLane);
        const float hi = __shfl(R[kt + 1][r], srcLane);
        S[kt][r] += (l16 > q4r) ? hi : lo;
      }
    }

    // online softmax (rows wave-private; 16 lanes share a row)
    float alpha[4];
#pragma unroll
    for (int r = 0; r < 4; ++r) {
      float mx = fmaxf(fmaxf(S[0][r], S[1][r]), fmaxf(S[2][r], S[3][r]));
#pragma unroll
      for (int off = 8; off > 0; off >>= 1) mx = fmaxf(mx, __shfl_xor(mx, off));
      const float nm = fmaxf(mrow[r], mx);
      alpha[r] = __expf(mrow[r] - nm);
      mrow[r] = nm;
      float ps = 0.f;
#pragma unroll
      for (int kt = 0; kt < 4; ++kt) {
        const float p = __expf(S[kt][r] - nm);
        S[kt][r] = p;
        ps += p;
      }
#pragma unroll
      for (int off = 8; off > 0; off >>= 1) ps += __shfl_xor(ps, off);
      lrow[r] = lrow[r] * alpha[r] + ps;
    }
    // publish P (A-layout source) + alpha
#pragma unroll
    for (int kt = 0; kt < 4; ++kt) {
#pragma unroll
      for (int r = 0; r < 4; ++r) {
        const int row = w * 16 + quad * 4 + r;
        Ptile[row * 72 + kt * 16 + l16] = __float2bfloat16(S[kt][r]);
      }
    }
    if (l16 == 0) {
#pragma unroll
      for (int r = 0; r < 4; ++r) alphaS[w * 16 + quad * 4 + r] = alpha[r];
    }
    __syncthreads();  // B4: Ptile/alphaS visible; all K/rK reads long done

    // prefetch next K/rK stage: DMA flies across PV + next B2
    if (t + 1 < 24) stage(t + 1);

    // rescale O with per-row alphas
#pragma unroll
    for (int qf = 0; qf < 4; ++qf) {
      const floatx4 al = *(const floatx4*)(alphaS + qf * 16 + quad * 4);
#pragma unroll
      for (int vtl = 0; vtl < 3; ++vtl)
#pragma unroll
        for (int r = 0; r < 4; ++r) Oacc[qf * 3 + vtl][r] *= al[r];
    }

    // PV: wave w owns vt tiles w*3..w*3+2 (V in regs), all 4 q-frags from Ptile
    short8 aP[4][2];
#pragma unroll
    for (int qf = 0; qf < 4; ++qf)
#pragma unroll
      for (int ks = 0; ks < 2; ++ks)
        aP[qf][ks] = *(const short8*)(Ptile + (qf * 16 + l16) * 72 + ks * 32 + quad * 8);

    __builtin_amdgcn_s_setprio(1);
#pragma unroll
    for (int vtl = 0; vtl < 3; ++vtl) {
#pragma unroll
      for (int ks = 0; ks < 2; ++ks) {
#pragma unroll
        for (int qf = 0; qf < 4; ++qf)
          Oacc[qf * 3 + vtl] = __builtin_amdgcn_mfma_f32_16x16x32_bf16(aP[qf][ks], vReg[vtl][ks], Oacc[qf * 3 + vtl], 0, 0, 0);
      }
    }
    __builtin_amdgcn_s_setprio(0);
  }

  // epilogue: broadcast lsum, normalize, store bf16
  if (l16 == 0) {
#pragma unroll
    for (int r = 0; r < 4; ++r) lrowS[w * 16 + quad * 4 + r] = lrow[r];
  }
  __syncthreads();
#pragma unroll
  for (int qf = 0; qf < 4; ++qf) {
    const floatx4 lv = *(const floatx4*)(lrowS + qf * 16 + quad * 4);
#pragma unroll
    for (int r = 0; r < 4; ++r) {
      const float inv = 1.f / lv[r];
      const int qrow = q0 + qf * 16 + quad * 4 + r;
      __hip_bfloat16* op = O + (size_t)(b * TT + qrow) * 1536 + h * 192 + w * 48;
#pragma unroll
      for (int vtl = 0; vtl < 3; ++vtl)
        op[vtl * 16 + l16] = __float2bfloat16(Oacc[qf * 3 + vtl][r] * inv);
    }
  }
}

// ---------------------------------------------------------------------------
extern "C" void kernel_launch(void* const* d_in, const int* in_sizes, int n_in,
                              void* d_out, int out_size, void* d_ws, size_t ws_size,
                              hipStream_t stream) {
  const void* x     = d_in[0];
  const void* W_q   = d_in[1];
  const void* W_k   = d_in[2];
  const void* W_v   = d_in[3];
  const void* W_rel = d_in[4];
  const void* W_out = d_in[5];
  const void* b_out = d_in[6];
  const void* r_w_b = d_in[7];
  const void* r_r_b = d_in[8];

  float* ws = (float*)d_ws;
  int*    flag = (int*)d_ws;                     // 16 floats reserved
  double* gmax = (double*)(ws + 16);             // 64 floats
  float* pe    = ws + 16 + 64;                   // 3071*192
  float* WrelF = pe    + (size_t)LREL * 192;     // 192*512
  float* boutF = WrelF + (size_t)192 * 512;      // 1536
  float* rwbF  = boutF + 1536;                   // 512
  float* rrbF  = rwbF + 512;                     // 512
  float* tmpQ  = rrbF + 512;                     // 6144*512 fp32
  __hip_bfloat16* xBf  = (__hip_bfloat16*)(tmpQ + (size_t)MROWS * 512);  // 6144*1536
  __hip_bfloat16* WqT  = xBf  + (size_t)MROWS * 1536;     // 512*1536
  __hip_bfloat16* WkT  = WqT  + (size_t)512 * 1536;       // 512*1536 (contiguous after WqT!)
  __hip_bfloat16* WvT  = WkT  + (size_t)512 * 1536;       // 1536*1536 (contiguous: QKV fused Bt)
  __hip_bfloat16* WoT  = WvT  + (size_t)1536 * 1536;      // 1536*1536
  __hip_bfloat16* Kbf  = WoT  + (size_t)1536 * 1536;      // 6144*512
  __hip_bfloat16* Vbf  = Kbf  + (size_t)MROWS * 512;      // 6144*1536
  __hip_bfloat16* Vfrag= Vbf  + (size_t)MROWS * 1536;     // 32*24*12*2*512 = 9,437,184
  __hip_bfloat16* Obf  = Vfrag + (size_t)32 * 192 * 1536; // 6144*1536
  __hip_bfloat16* rKl  = Obf  + (size_t)MROWS * 1536;     // 8*3071*64
  char* endp = (char*)(rKl + (size_t)HH * LREL * 64);
  if (ws_size < (size_t)(endp - (char*)d_ws)) return;  // ws too small

  // frag-packed K / rK overlay xBf (free after the QKV GEMM; 4.7M <= 9.4M elems)
  __hip_bfloat16* Kfrag  = xBf;                          // 32*96*2*512 = 3,145,728
  __hip_bfloat16* rKfrag = xBf + (size_t)3145728;        // 8*192*2*512 = 1,572,864

  detect_kernel<<<1, 64, 0, stream>>>(x, flag);

  auto conv = [&](const void* src, float* dst, int n) {
    convert_kernel<<<(n + 255) / 256, 256, 0, stream>>>(src, dst, n, flag);
  };
  conv(W_rel, WrelF, 192 * 512);
  conv(b_out, boutF, 1536);
  conv(r_w_b, rwbF,  512);
  conv(r_r_b, rrbF,  512);

  convbf_kernel<<<(MROWS * 1536 + 255) / 256, 256, 0, stream>>>(x, xBf, MROWS * 1536, flag);

  // weight transposes: src [K,N] -> dst [N,K] bf16
  wt_kernel<<<dim3(512 / 64, 1536 / 64), 256, 0, stream>>>(W_q, WqT, 1536, 512, flag);
  wt_kernel<<<dim3(512 / 64, 1536 / 64), 256, 0, stream>>>(W_k, WkT, 1536, 512, flag);
  wt_kernel<<<dim3(1536 / 64, 1536 / 64), 256, 0, stream>>>(W_v, WvT, 1536, 1536, flag);
  wt_kernel<<<dim3(1536 / 64, 1536 / 64), 256, 0, stream>>>(W_out, WoT, 1536, 1536, flag);

  gmax_kernel<<<32, 256, 0, stream>>>(gmax);
  pe_kernel<<<LREL, 192, 0, stream>>>(pe, gmax);
  relk_kernel<<<(LREL + 7) / 8, 512, 0, stream>>>(pe, WrelF, rKl);

  // fused Q+K+V projection: Bt spans [WqT; WkT; WvT] (contiguous), N=2560;
  // Q -> fp32 tmpQ, K -> bf16 Kbf, V -> bf16 Vbf (col-range uniform per block).
  gemm_mfma<3, false><<<dim3(2560 / 128, MROWS / 128), 256, 0, stream>>>(
      xBf, WqT, tmpQ, Kbf, Vbf, nullptr, MROWS, 2560, CC, flag);

  // fragment packs (kfrag/rkfrag overwrite xBf -> must follow the QKV GEMM)
  kfrag_kernel<<<1536, 256, 0, stream>>>(Kbf, Kfrag);
  rkfrag_kernel<<<768, 256, 0, stream>>>(rKl, rKfrag);
  vfrag_kernel<<<2304, 256, 0, stream>>>(Vbf, Vfrag);

  attn_frag<<<768, 256, 0, stream>>>(tmpQ, rwbF, rrbF, Kfrag, rKfrag, Vfrag, Obf);

  gemm_mfma<2, true><<<dim3(1536 / 128, MROWS / 128), 256, 0, stream>>>(
      Obf, WoT, d_out, nullptr, nullptr, boutF, MROWS, 1536, CC, flag);
}

// Round 9
// 432.819 us; speedup vs baseline: 1.2660x; 1.2660x over previous
//
#include <hip/hip_runtime.h>
#include <hip/hip_bf16.h>
#include <math.h>

// Problem constants
#define BB 4
#define TT 1536
#define CC 1536
#define HH 8
#define DKk 64
#define DVv 192
#define NBASIS 32
#define LREL 3071          // 2T-1
#define MROWS 6144         // B*T

typedef short short8 __attribute__((ext_vector_type(8)));
typedef float floatx4 __attribute__((ext_vector_type(4)));

static __device__ inline short f2bf(float f) {
  __hip_bfloat16 h = __float2bfloat16(f);
  return *reinterpret_cast<short*>(&h);
}

// async global->LDS, 16B per lane; LDS dest = wave-uniform base + lane*16
static __device__ inline void gload_lds16(const __hip_bfloat16* g, __hip_bfloat16* l) {
  __builtin_amdgcn_global_load_lds(
      (const __attribute__((address_space(1))) unsigned int*)g,
      (__attribute__((address_space(3))) unsigned int*)l, 16, 0, 0);
}

// ---------------------------------------------------------------------------
// Stage 0: dtype detection (fp32 vs bf16 input payloads).
// ---------------------------------------------------------------------------
__global__ void detect_kernel(const void* __restrict__ x, int* __restrict__ flag) {
  if (threadIdx.x == 0 && blockIdx.x == 0) {
    const __hip_bfloat16* h = (const __hip_bfloat16*)x;
    int cnt = 0;
    for (int i = 0; i < 64; ++i) {
      float v = fabsf((float)h[2 * i]);
      if (v > 1e-5f && v < 256.0f) cnt++;
    }
    *flag = (cnt >= 32) ? 1 : 0;  // 1 => inputs are bf16
  }
}

__global__ __launch_bounds__(256) void convert_kernel(const void* __restrict__ src,
                                                      float* __restrict__ dst, int n,
                                                      const int* __restrict__ flag) {
  const int i = blockIdx.x * 256 + threadIdx.x;
  if (i >= n) return;
  if (*flag) dst[i] = (float)((const __hip_bfloat16*)src)[i];
  else       dst[i] = ((const float*)src)[i];
}

__global__ __launch_bounds__(256) void convbf_kernel(const void* __restrict__ src,
                                                     __hip_bfloat16* __restrict__ dst, int n,
                                                     const int* __restrict__ flag) {
  const int i = blockIdx.x * 256 + threadIdx.x;
  if (i >= n) return;
  if (*flag) dst[i] = ((const __hip_bfloat16*)src)[i];
  else       dst[i] = __float2bfloat16(((const float*)src)[i]);
}

// ---------------------------------------------------------------------------
// Weight transpose: src [K,N] (fp32/bf16 per flag) -> dst bf16 [N,K]
// ---------------------------------------------------------------------------
__global__ __launch_bounds__(256) void wt_kernel(const void* __restrict__ src,
                                                 __hip_bfloat16* __restrict__ dst,
                                                 int K, int N, const int* __restrict__ flag) {
  __shared__ __hip_bfloat16 tile[64][68];
  const int tid = threadIdx.x;
  const int k0 = blockIdx.y * 64, n0 = blockIdx.x * 64;
  const bool bf = (*flag != 0);
  {
    const int r = tid >> 2, c0 = (tid & 3) * 16;
    if (bf) {
      const __hip_bfloat16* sp = (const __hip_bfloat16*)src + (size_t)(k0 + r) * N + n0 + c0;
#pragma unroll
      for (int u = 0; u < 16; ++u) tile[r][c0 + u] = sp[u];
    } else {
      const float* sp = (const float*)src + (size_t)(k0 + r) * N + n0 + c0;
#pragma unroll
      for (int u = 0; u < 16; ++u) tile[r][c0 + u] = __float2bfloat16(sp[u]);
    }
  }
  __syncthreads();
  {
    const int nr = tid >> 2, c0 = (tid & 3) * 16;
    __hip_bfloat16* dp = dst + (size_t)(n0 + nr) * K + k0 + c0;
#pragma unroll
    for (int u = 0; u < 16; ++u) dp[u] = tile[c0 + u][nr];
  }
}

// ---------------------------------------------------------------------------
// Stage 1: gamma-basis max over pos (fp64). One block per basis j.
// ---------------------------------------------------------------------------
__global__ void gmax_kernel(double* __restrict__ gmax) {
  const int j = blockIdx.x;
  const double mean = 48.0 + 1488.0 * (double)j / 31.0;
  const double conc = (mean / 24.0) * (mean / 24.0);
  const double rate = mean / 576.0;
  const double log_norm = lgamma(conc) - conc * log(rate);
  double mx = 1e-8;
  for (int pos = 1 + threadIdx.x; pos <= 1535; pos += 256) {
    double p = exp((conc - 1.0) * log((double)pos) - rate * (double)pos - log_norm) + 1e-8;
    mx = fmax(mx, p);
  }
  __shared__ double red[256];
  red[threadIdx.x] = mx;
  __syncthreads();
  for (int s = 128; s > 0; s >>= 1) {
    if (threadIdx.x < s) red[threadIdx.x] = fmax(red[threadIdx.x], red[threadIdx.x + s]);
    __syncthreads();
  }
  if (threadIdx.x == 0) gmax[j] = red[0];
}

// ---------------------------------------------------------------------------
// Stage 2: pe[l, f], fp64 math, fp32 store.
// ---------------------------------------------------------------------------
__global__ void pe_kernel(float* __restrict__ pe, const double* __restrict__ gmax) {
  const int l = blockIdx.x;
  const int f = threadIdx.x;  // 0..191
  const int dist = l - (TT - 1);
  const int pos = dist < 0 ? -dist : dist;
  const int base = f % 96;
  const int cls = base / 32;
  const int j = base % 32;
  double v;
  if (cls == 0) {
    const double max_range = log(1536.0) / log(2.0);
    const double e = 3.0 + (max_range - 3.0) * (double)j / 31.0;
    const double hl = exp2(e);
    v = exp2(-(double)pos / hl);
  } else if (cls == 1) {
    const double width = exp2((double)(j + 1)) - 1.0;
    v = (width > (double)pos) ? 1.0 : 0.0;
  } else {
    const double mean = 48.0 + 1488.0 * (double)j / 31.0;
    const double conc = (mean / 24.0) * (mean / 24.0);
    const double rate = mean / 576.0;
    double p;
    if (pos == 0) {
      p = 1e-8;
    } else {
      const double log_norm = lgamma(conc) - conc * log(rate);
      p = exp((conc - 1.0) * log((double)pos) - rate * (double)pos - log_norm) + 1e-8;
    }
    v = p / gmax[j];
  }
  float out = (float)v;
  if (f >= 96) {
    float sgn = (dist > 0) ? 1.f : (dist < 0 ? -1.f : 0.f);
    out *= sgn;
  }
  pe[(size_t)l * 192 + f] = out;
}

// ---------------------------------------------------------------------------
// Stage 3: rKl[h][l][d] (bf16) = sum_f pe[l,f] * W_rel_k[f, h*64+d]
// ---------------------------------------------------------------------------
__global__ __launch_bounds__(512) void relk_kernel(const float* __restrict__ pe,
                                                   const float* __restrict__ Wrk,
                                                   __hip_bfloat16* __restrict__ rKl) {
  __shared__ float pes[8][192];
  const int l0 = blockIdx.x * 8;
  const int nrows = (LREL - l0) < 8 ? (LREL - l0) : 8;
  const int tid = threadIdx.x;
  for (int idx = tid; idx < nrows * 192; idx += 512) {
    int r = idx / 192, f = idx % 192;
    pes[r][f] = pe[(size_t)(l0 + r) * 192 + f];
  }
  __syncthreads();
  float acc[8] = {0.f, 0.f, 0.f, 0.f, 0.f, 0.f, 0.f, 0.f};
  for (int f = 0; f < 192; ++f) {
    float w = Wrk[(size_t)f * 512 + tid];
#pragma unroll
    for (int r = 0; r < 8; ++r) acc[r] += pes[r][f] * w;
  }
  const int h = tid >> 6, d = tid & 63;
  for (int r = 0; r < nrows; ++r)
    rKl[((size_t)h * LREL + (l0 + r)) * 64 + d] = __float2bfloat16(acc[r]);
}

// ---------------------------------------------------------------------------
// bf16 MFMA GEMM, BK=64, XOR granule swizzle, XCD-bijective block swizzle
// (m204 formula; grids here always have nwg % 8 == 0).
//   C[M,N] = A[M,K] @ Bt[N,K]^T ; 128x128 tile, 4 waves.
// MODE 2: d_out per flag (+bias); MODE 3: fused QKV (N=2560):
//   cols<512 -> fp32 Cout; 512..1023 -> bf16 Cout2; >=1024 -> bf16 Cout3.
// ---------------------------------------------------------------------------
template <int MODE, bool BIAS>
__global__ __launch_bounds__(256) void gemm_mfma(const __hip_bfloat16* __restrict__ A,
                                                 const __hip_bfloat16* __restrict__ Bt,
                                                 void* __restrict__ Cout,
                                                 void* __restrict__ Cout2,
                                                 void* __restrict__ Cout3,
                                                 const float* __restrict__ bias,
                                                 int M, int N, int K,
                                                 const int* __restrict__ flag) {
  __shared__ __align__(16) __hip_bfloat16 As[128 * 64];
  __shared__ __align__(16) __hip_bfloat16 Bs[128 * 64];
  const int tid = threadIdx.x;
  const int w = tid >> 6, lane = tid & 63;
  const int quad = lane >> 4, l16 = lane & 15;
  const int wm = w >> 1, wn = w & 1;
  // XCD-bijective swizzle: o = (id%8)*(nwg/8) + id/8 (bijective since nwg%8==0)
  const int gx = gridDim.x;
  const int nwg = gx * gridDim.y;
  const int id = blockIdx.y * gx + blockIdx.x;
  const int o = (id & 7) * (nwg >> 3) + (id >> 3);
  const int row0 = (o / gx) * 128, col0 = (o % gx) * 128;

  const floatx4 vzero = {0.f, 0.f, 0.f, 0.f};
  floatx4 acc[4][4];
#pragma unroll
  for (int i = 0; i < 4; ++i)
#pragma unroll
    for (int j = 0; j < 4; ++j) acc[i][j] = vzero;

  // staging: each wave stages 32 rows of A and B (4 x 1KB chunks each).
  // chunk covers 8 rows; sr = row within chunk; source granule pre-swizzled.
  const int sr = lane >> 3;              // 0..7
  const int sg = (lane & 7) ^ sr;        // swizzled 8-elem granule
  const __hip_bfloat16* ag = A + (size_t)(row0 + w * 32 + sr) * K + sg * 8;
  const __hip_bfloat16* bg = Bt + (size_t)(col0 + w * 32 + sr) * K + sg * 8;
  __hip_bfloat16* as_ = As + w * 32 * 64;
  __hip_bfloat16* bs_ = Bs + w * 32 * 64;

  for (int k0 = 0; k0 < K; k0 += 64) {
    __syncthreads();
#pragma unroll
    for (int i = 0; i < 4; ++i) {
      gload_lds16(ag + (size_t)(i * 8) * K + k0, as_ + i * 8 * 64);
      gload_lds16(bg + (size_t)(i * 8) * K + k0, bs_ + i * 8 * 64);
    }
    __syncthreads();
#pragma unroll
    for (int ks = 0; ks < 2; ++ks) {
      const int xr = (((ks * 4 + quad) ^ (l16 & 7)) << 3);
      short8 aF[4], bF[4];
#pragma unroll
      for (int mt = 0; mt < 4; ++mt)
        aF[mt] = *(const short8*)(As + (wm * 64 + mt * 16 + l16) * 64 + xr);
#pragma unroll
      for (int nt = 0; nt < 4; ++nt)
        bF[nt] = *(const short8*)(Bs + (wn * 64 + nt * 16 + l16) * 64 + xr);
#pragma unroll
      for (int mt = 0; mt < 4; ++mt)
#pragma unroll
        for (int nt = 0; nt < 4; ++nt)
          acc[mt][nt] = __builtin_amdgcn_mfma_f32_16x16x32_bf16(aF[mt], bF[nt], acc[mt][nt], 0, 0, 0);
    }
  }

  const bool obf = (MODE == 2) ? (*flag != 0) : false;
#pragma unroll
  for (int mt = 0; mt < 4; ++mt) {
#pragma unroll
    for (int r = 0; r < 4; ++r) {
      const int row = row0 + wm * 64 + mt * 16 + quad * 4 + r;
#pragma unroll
      for (int nt = 0; nt < 4; ++nt) {
        const int col = col0 + wn * 64 + nt * 16 + l16;
        float v = acc[mt][nt][r];
        if (BIAS) v += bias[col];
        if (MODE == 0) {
          ((float*)Cout)[(size_t)row * N + col] = v;
        } else if (MODE == 1) {
          ((__hip_bfloat16*)Cout)[(size_t)row * N + col] = __float2bfloat16(v);
        } else if (MODE == 2) {
          if (obf) ((__hip_bfloat16*)Cout)[(size_t)row * N + col] = __float2bfloat16(v);
          else     ((float*)Cout)[(size_t)row * N + col] = v;
        } else {  // MODE 3: Q fp32 | K bf16 | V bf16
          if (col < 512)
            ((float*)Cout)[(size_t)row * 512 + col] = v;
          else if (col < 1024)
            ((__hip_bfloat16*)Cout2)[(size_t)row * 512 + (col - 512)] = __float2bfloat16(v);
          else
            ((__hip_bfloat16*)Cout3)[(size_t)row * 1536 + (col - 1024)] = __float2bfloat16(v);
        }
      }
    }
  }
}

// ---------------------------------------------------------------------------
// K fragment pack: Kbf [b*T+t][h*64+d] -> Kfrag words [bh][ktile(96)][ks(2)][lane][8]
// ---------------------------------------------------------------------------
__global__ __launch_bounds__(256) void kfrag_kernel(const __hip_bfloat16* __restrict__ Kbf,
                                                    __hip_bfloat16* __restrict__ Kfrag) {
  const int widx = blockIdx.x * 256 + threadIdx.x;   // < 32*96*2*64 = 393216
  const int lane = widx & 63;
  const int ks = (widx >> 6) & 1;
  const int kt = (widx >> 7) % 96;
  const int bh = (widx >> 7) / 96;
  const int b = bh >> 3, h = bh & 7;
  const __hip_bfloat16* src = Kbf + ((size_t)(b * TT + kt * 16 + (lane & 15))) * 512
                              + h * 64 + ks * 32 + (lane >> 4) * 8;
  *(uint4*)(Kfrag + (size_t)widx * 8) = *(const uint4*)src;
}

// ---------------------------------------------------------------------------
// rK fragment pack: rKl [h*3071+l][64] -> rKfrag words [h][lt(192)][ks(2)][lane][8]
// ---------------------------------------------------------------------------
__global__ __launch_bounds__(256) void rkfrag_kernel(const __hip_bfloat16* __restrict__ rKl,
                                                     __hip_bfloat16* __restrict__ rKfrag) {
  const int widx = blockIdx.x * 256 + threadIdx.x;   // < 8*192*2*64 = 196608
  const int lane = widx & 63;
  const int ks = (widx >> 6) & 1;
  const int lt = (widx >> 7) % 192;
  const int h = (widx >> 7) / 192;
  int l = lt * 16 + (lane & 15);
  if (l > 3070) l = 3070;   // row l=3071 is fetched but never consumed (j<=126)
  const __hip_bfloat16* src = rKl + ((size_t)h * LREL + l) * 64 + ks * 32 + (lane >> 4) * 8;
  *(uint4*)(rKfrag + (size_t)widx * 8) = *(const uint4*)src;
}

// ---------------------------------------------------------------------------
// V fragment pack: Vbf [b*T+t][h*192+v] -> Vfrag words [bh][kb(24)][vt(12)][ks(2)][lane][8]
// ---------------------------------------------------------------------------
__global__ __launch_bounds__(256) void vfrag_kernel(const __hip_bfloat16* __restrict__ Vbf,
                                                    __hip_bfloat16* __restrict__ Vfrag) {
  int bid = blockIdx.x;            // 4*8*24*3 = 2304
  int vt3 = bid % 3; int kb = (bid / 3) % 24; int h = (bid / 72) & 7; int b = bid / 576;
  const int bh = b * 8 + h;
  __shared__ __hip_bfloat16 tile[64][72];   // [t][v]
  const int tid = threadIdx.x;
  {
    int r = tid >> 2, c0 = (tid & 3) * 16;   // r: t-row, c: v-col
    const __hip_bfloat16* src = Vbf + (size_t)(b * TT + kb * 64 + r) * 1536 + h * 192 + vt3 * 64 + c0;
#pragma unroll
    for (int u = 0; u < 16; ++u) tile[r][c0 + u] = src[u];
  }
  __syncthreads();
#pragma unroll
  for (int u = 0; u < 2; ++u) {
    const int w512 = u * 256 + tid;          // 0..511 words of this tile
    const int vtl = w512 >> 7;               // 0..3 (local v-tile)
    const int ks = (w512 >> 6) & 1;
    const int ln = w512 & 63;
    const int qd = ln >> 4, s16 = ln & 15;
    union { uint4 u4; unsigned short us[8]; } pk;
#pragma unroll
    for (int j = 0; j < 8; ++j)
      pk.us[j] = *(const unsigned short*)&tile[ks * 32 + qd * 8 + j][vtl * 16 + s16];
    __hip_bfloat16* dst = Vfrag +
        (((size_t)(bh * 24 + kb) * 12 + vt3 * 4 + vtl) * 2 + ks) * 512 + (size_t)ln * 8;
    *(uint4*)dst = pk.u4;
  }
}

// ---------------------------------------------------------------------------
// MFMA flash attention — 2-barrier pipelined skeleton + in-register shuffle
// diagonal gather (Rbuf eliminated; conflicts 4.7e6 -> 2.4e6 confirmed r8).
// FIX vs round 8: __launch_bounds__(256,3) — the (256,4) bound capped VGPR
// at 64 and caused massive scratch spills (FETCH 320MB / WRITE 413MB).
// At natural ~84 VGPR the limits are: VGPR -> 4 waves/SIMD; LDS 34304B ->
// 4 blocks/CU. Occupancy target reached WITHOUT strangling the allocator.
// ---------------------------------------------------------------------------
__global__ __launch_bounds__(256, 3) void attn_frag(
    const float* __restrict__ tmpQ,                 // [b*T+t][512] fp32
    const float* __restrict__ rwb,                  // [512]
    const float* __restrict__ rrb,                  // [512]
    const __hip_bfloat16* __restrict__ Kfrag,       // [bh][96][2][64][8]
    const __hip_bfloat16* __restrict__ rKfrag,      // [h][192][2][64][8]
    const __hip_bfloat16* __restrict__ Vfrag,       // [bh][24][12][2][64][8]
    __hip_bfloat16* __restrict__ O)                 // [b*T+q][1536] bf16
{
  const int tid = threadIdx.x;
  const int w = tid >> 6, lane = tid & 63;
  const int quad = lane >> 4, l16 = lane & 15;
  const int le8 = lane * 8;   // elem offset of this lane within a fragment word
  // XCD-bijective swizzle (768 % 8 == 0): 96 consecutive logical blocks/XCD.
  const int o = (blockIdx.x & 7) * 96 + (blockIdx.x >> 3);
  const int qt = o % 24;
  const int h = (o / 24) & 7;
  const int b = o / 192;
  const int bh = b * 8 + h;
  const int q0 = qt * 64;

  // LDS (bytes): Klds @0 (8192) | rKlds @8192 (16384) | Ptile @24576 (9216)
  //              alphaS @33792 (256) | lrowS @34048 (256).  Total 34304.
  __shared__ __align__(16) char sm[34304];
  __hip_bfloat16* Klds  = (__hip_bfloat16*)sm;
  __hip_bfloat16* rKlds = (__hip_bfloat16*)(sm + 8192);
  __hip_bfloat16* Ptile = (__hip_bfloat16*)(sm + 24576);
  float* alphaS = (float*)(sm + 33792);
  float* lrowS  = (float*)(sm + 34048);

  // Q fragments (A-layout): lane holds A[m=l16][k=quad*8+j], kstep*32 offset.
  short8 aQw[2], aQr[2];
  {
    const int qrow = q0 + w * 16 + l16;
    const float* qp = tmpQ + (size_t)(b * TT + qrow) * 512 + h * 64;
#pragma unroll
    for (int ks = 0; ks < 2; ++ks) {
#pragma unroll
      for (int j = 0; j < 8; ++j) {
        const int d = ks * 32 + quad * 8 + j;
        const float qv = qp[d] * 0.125f;
        aQw[ks][j] = f2bf(qv + rwb[h * 64 + d]);
        aQr[ks][j] = f2bf(qv + rrb[h * 64 + d]);
      }
    }
  }

  const floatx4 vzero = {0.f, 0.f, 0.f, 0.f};
  floatx4 Oacc[12];   // [qf(4)][vtl(3)] : rows qf*16+quad*4+r, cols (w*3+vtl)*16+l16
#pragma unroll
  for (int i = 0; i < 12; ++i) Oacc[i] = vzero;
  float mrow[4], lrow[4];
#pragma unroll
  for (int r = 0; r < 4; ++r) { mrow[r] = -INFINITY; lrow[r] = 0.f; }

  // staging source pointers: kSrc/rSrc carry the per-lane 16B granule (le8)
  // because gload_lds takes per-lane GLOBAL addresses. vSrc does NOT (plain
  // vector loads add le8 at the read site).
  const __hip_bfloat16* kSrc = Kfrag + (size_t)bh * 98304 + le8;
  const __hip_bfloat16* rSrc = rKfrag + (size_t)h * 196608
                               + (size_t)((1472 - q0) >> 4) * 1024 + le8;
  const __hip_bfloat16* vSrc = Vfrag + (size_t)bh * 294912;

  const int jt0 = 3 - w;   // wave w consumes jt tiles jt0..jt0+4 only

  // K(8 words) + rK(16 words) staged per iter; 6 gload_lds per wave.
  auto stage = [&](int t) {
    const __hip_bfloat16* kIt = kSrc + (size_t)(t * 4) * 1024;
    const __hip_bfloat16* rIt = rSrc + (size_t)(t * 4) * 1024;
    if (w == 0) {
#pragma unroll
      for (int i = 0; i < 6; ++i) gload_lds16(kIt + i * 512, Klds + i * 512);
    } else if (w == 1) {
#pragma unroll
      for (int i = 6; i < 8; ++i) gload_lds16(kIt + i * 512, Klds + i * 512);
#pragma unroll
      for (int i = 0; i < 4; ++i) gload_lds16(rIt + i * 512, rKlds + i * 512);
    } else if (w == 2) {
#pragma unroll
      for (int i = 4; i < 10; ++i) gload_lds16(rIt + i * 512, rKlds + i * 512);
    } else {
#pragma unroll
      for (int i = 10; i < 16; ++i) gload_lds16(rIt + i * 512, rKlds + i * 512);
    }
  };

  stage(0);  // prologue

  for (int t = 0; t < 24; ++t) {
    __syncthreads();  // B2: stage(t) DMA drained+visible; Ptile(t-1) PV reads done

    // V fragments straight into regs (hidden under QK/R MFMAs below)
    short8 vReg[3][2];
    {
      const __hip_bfloat16* vIt = vSrc + (size_t)t * 12288;
#pragma unroll
      for (int vtl = 0; vtl < 3; ++vtl)
#pragma unroll
        for (int ks = 0; ks < 2; ++ks)
          vReg[vtl][ks] = *(const short8*)(vIt + ((w * 3 + vtl) * 2 + ks) * 512 + le8);
    }

    floatx4 S[4], R[5];
#pragma unroll
    for (int i = 0; i < 4; ++i) S[i] = vzero;
#pragma unroll
    for (int i = 0; i < 5; ++i) R[i] = vzero;

    __builtin_amdgcn_s_setprio(1);
#pragma unroll
    for (int kt = 0; kt < 4; ++kt) {
#pragma unroll
      for (int ks = 0; ks < 2; ++ks) {
        short8 bK = *(const short8*)(Klds + (kt * 2 + ks) * 512 + le8);
        S[kt] = __builtin_amdgcn_mfma_f32_16x16x32_bf16(aQw[ks], bK, S[kt], 0, 0, 0);
      }
    }
#pragma unroll
    for (int i = 0; i < 5; ++i) {
      const int jt = jt0 + i;
#pragma unroll
      for (int ks = 0; ks < 2; ++ks) {
        short8 bR = *(const short8*)(rKlds + (jt * 2 + ks) * 512 + le8);
        R[i] = __builtin_amdgcn_mfma_f32_16x16x32_bf16(aQr[ks], bR, R[i], 0, 0, 0);
      }
    }
    __builtin_amdgcn_s_setprio(0);

    // in-register diagonal shift gather: S[kt][r] += R[kt+(l16>q4r)][r]
    // from lane (lane&48) + ((l16-q4r-1)&15)  (same quad, compile-time regs)
#pragma unroll
    for (int kt = 0; kt < 4; ++kt) {
#pragma unroll
      for (int r = 0; r < 4; ++r) {
        const int q4r = quad * 4 + r;
        const int srcLane = (lane & 48) + ((l16 - q4r - 1) & 15);
        const float lo = __shfl(R[kt][r], srcLane);
        const float hi = __shfl(R[kt + 1][r], srcLane);
        S[kt][r] += (l16 > q4r) ? hi : lo;
      }
    }

    // online softmax (rows wave-private; 16 lanes share a row)
    float alpha[4];
#pragma unroll
    for (int r = 0; r < 4; ++r) {
      float mx = fmaxf(fmaxf(S[0][r], S[1][r]), fmaxf(S[2][r], S[3][r]));
#pragma unroll
      for (int off = 8; off > 0; off >>= 1) mx = fmaxf(mx, __shfl_xor(mx, off));
      const float nm = fmaxf(mrow[r], mx);
      alpha[r] = __expf(mrow[r] - nm);
      mrow[r] = nm;
      float ps = 0.f;
#pragma unroll
      for (int kt = 0; kt < 4; ++kt) {
        const float p = __expf(S[kt][r] - nm);
        S[kt][r] = p;
        ps += p;
      }
#pragma unroll
      for (int off = 8; off > 0; off >>= 1) ps += __shfl_xor(ps, off);
      lrow[r] = lrow[r] * alpha[r] + ps;
    }
    // publish P (A-layout source) + alpha
#pragma unroll
    for (int kt = 0; kt < 4; ++kt) {
#pragma unroll
      for (int r = 0; r < 4; ++r) {
        const int row = w * 16 + quad * 4 + r;
        Ptile[row * 72 + kt * 16 + l16] = __float2bfloat16(S[kt][r]);
      }
    }
    if (l16 == 0) {
#pragma unroll
      for (int r = 0; r < 4; ++r) alphaS[w * 16 + quad * 4 + r] = alpha[r];
    }
    __syncthreads();  // B4: Ptile/alphaS visible; all K/rK reads long done

    // prefetch next K/rK stage: DMA flies across PV + next B2
    if (t + 1 < 24) stage(t + 1);

    // rescale O with per-row alphas
#pragma unroll
    for (int qf = 0; qf < 4; ++qf) {
      const floatx4 al = *(const floatx4*)(alphaS + qf * 16 + quad * 4);
#pragma unroll
      for (int vtl = 0; vtl < 3; ++vtl)
#pragma unroll
        for (int r = 0; r < 4; ++r) Oacc[qf * 3 + vtl][r] *= al[r];
    }

    // PV: wave w owns vt tiles w*3..w*3+2 (V in regs), all 4 q-frags from Ptile
    short8 aP[4][2];
#pragma unroll
    for (int qf = 0; qf < 4; ++qf)
#pragma unroll
      for (int ks = 0; ks < 2; ++ks)
        aP[qf][ks] = *(const short8*)(Ptile + (qf * 16 + l16) * 72 + ks * 32 + quad * 8);

    __builtin_amdgcn_s_setprio(1);
#pragma unroll
    for (int vtl = 0; vtl < 3; ++vtl) {
#pragma unroll
      for (int ks = 0; ks < 2; ++ks) {
#pragma unroll
        for (int qf = 0; qf < 4; ++qf)
          Oacc[qf * 3 + vtl] = __builtin_amdgcn_mfma_f32_16x16x32_bf16(aP[qf][ks], vReg[vtl][ks], Oacc[qf * 3 + vtl], 0, 0, 0);
      }
    }
    __builtin_amdgcn_s_setprio(0);
  }

  // epilogue: broadcast lsum, normalize, store bf16
  if (l16 == 0) {
#pragma unroll
    for (int r = 0; r < 4; ++r) lrowS[w * 16 + quad * 4 + r] = lrow[r];
  }
  __syncthreads();
#pragma unroll
  for (int qf = 0; qf < 4; ++qf) {
    const floatx4 lv = *(const floatx4*)(lrowS + qf * 16 + quad * 4);
#pragma unroll
    for (int r = 0; r < 4; ++r) {
      const float inv = 1.f / lv[r];
      const int qrow = q0 + qf * 16 + quad * 4 + r;
      __hip_bfloat16* op = O + (size_t)(b * TT + qrow) * 1536 + h * 192 + w * 48;
#pragma unroll
      for (int vtl = 0; vtl < 3; ++vtl)
        op[vtl * 16 + l16] = __float2bfloat16(Oacc[qf * 3 + vtl][r] * inv);
    }
  }
}

// ---------------------------------------------------------------------------
extern "C" void kernel_launch(void* const* d_in, const int* in_sizes, int n_in,
                              void* d_out, int out_size, void* d_ws, size_t ws_size,
                              hipStream_t stream) {
  const void* x     = d_in[0];
  const void* W_q   = d_in[1];
  const void* W_k   = d_in[2];
  const void* W_v   = d_in[3];
  const void* W_rel = d_in[4];
  const void* W_out = d_in[5];
  const void* b_out = d_in[6];
  const void* r_w_b = d_in[7];
  const void* r_r_b = d_in[8];

  float* ws = (float*)d_ws;
  int*    flag = (int*)d_ws;                     // 16 floats reserved
  double* gmax = (double*)(ws + 16);             // 64 floats
  float* pe    = ws + 16 + 64;                   // 3071*192
  float* WrelF = pe    + (size_t)LREL * 192;     // 192*512
  float* boutF = WrelF + (size_t)192 * 512;      // 1536
  float* rwbF  = boutF + 1536;                   // 512
  float* rrbF  = rwbF + 512;                     // 512
  float* tmpQ  = rrbF + 512;                     // 6144*512 fp32
  __hip_bfloat16* xBf  = (__hip_bfloat16*)(tmpQ + (size_t)MROWS * 512);  // 6144*1536
  __hip_bfloat16* WqT  = xBf  + (size_t)MROWS * 1536;     // 512*1536
  __hip_bfloat16* WkT  = WqT  + (size_t)512 * 1536;       // 512*1536 (contiguous after WqT!)
  __hip_bfloat16* WvT  = WkT  + (size_t)512 * 1536;       // 1536*1536 (contiguous: QKV fused Bt)
  __hip_bfloat16* WoT  = WvT  + (size_t)1536 * 1536;      // 1536*1536
  __hip_bfloat16* Kbf  = WoT  + (size_t)1536 * 1536;      // 6144*512
  __hip_bfloat16* Vbf  = Kbf  + (size_t)MROWS * 512;      // 6144*1536
  __hip_bfloat16* Vfrag= Vbf  + (size_t)MROWS * 1536;     // 32*24*12*2*512 = 9,437,184
  __hip_bfloat16* Obf  = Vfrag + (size_t)32 * 192 * 1536; // 6144*1536
  __hip_bfloat16* rKl  = Obf  + (size_t)MROWS * 1536;     // 8*3071*64
  char* endp = (char*)(rKl + (size_t)HH * LREL * 64);
  if (ws_size < (size_t)(endp - (char*)d_ws)) return;  // ws too small

  // frag-packed K / rK overlay xBf (free after the QKV GEMM; 4.7M <= 9.4M elems)
  __hip_bfloat16* Kfrag  = xBf;                          // 32*96*2*512 = 3,145,728
  __hip_bfloat16* rKfrag = xBf + (size_t)3145728;        // 8*192*2*512 = 1,572,864

  detect_kernel<<<1, 64, 0, stream>>>(x, flag);

  auto conv = [&](const void* src, float* dst, int n) {
    convert_kernel<<<(n + 255) / 256, 256, 0, stream>>>(src, dst, n, flag);
  };
  conv(W_rel, WrelF, 192 * 512);
  conv(b_out, boutF, 1536);
  conv(r_w_b, rwbF,  512);
  conv(r_r_b, rrbF,  512);

  convbf_kernel<<<(MROWS * 1536 + 255) / 256, 256, 0, stream>>>(x, xBf, MROWS * 1536, flag);

  // weight transposes: src [K,N] -> dst [N,K] bf16
  wt_kernel<<<dim3(512 / 64, 1536 / 64), 256, 0, stream>>>(W_q, WqT, 1536, 512, flag);
  wt_kernel<<<dim3(512 / 64, 1536 / 64), 256, 0, stream>>>(W_k, WkT, 1536, 512, flag);
  wt_kernel<<<dim3(1536 / 64, 1536 / 64), 256, 0, stream>>>(W_v, WvT, 1536, 1536, flag);
  wt_kernel<<<dim3(1536 / 64, 1536 / 64), 256, 0, stream>>>(W_out, WoT, 1536, 1536, flag);

  gmax_kernel<<<32, 256, 0, stream>>>(gmax);
  pe_kernel<<<LREL, 192, 0, stream>>>(pe, gmax);
  relk_kernel<<<(LREL + 7) / 8, 512, 0, stream>>>(pe, WrelF, rKl);

  // fused Q+K+V projection: Bt spans [WqT; WkT; WvT] (contiguous), N=2560;
  // Q -> fp32 tmpQ, K -> bf16 Kbf, V -> bf16 Vbf (col-range uniform per block).
  gemm_mfma<3, false><<<dim3(2560 / 128, MROWS / 128), 256, 0, stream>>>(
      xBf, WqT, tmpQ, Kbf, Vbf, nullptr, MROWS, 2560, CC, flag);

  // fragment packs (kfrag/rkfrag overwrite xBf -> must follow the QKV GEMM)
  kfrag_kernel<<<1536, 256, 0, stream>>>(Kbf, Kfrag);
  rkfrag_kernel<<<768, 256, 0, stream>>>(rKl, rKfrag);
  vfrag_kernel<<<2304, 256, 0, stream>>>(Vbf, Vfrag);

  attn_frag<<<768, 256, 0, stream>>>(tmpQ, rwbF, rrbF, Kfrag, rKfrag, Vfrag, Obf);

  gemm_mfma<2, true><<<dim3(1536 / 128, MROWS / 128), 256, 0, stream>>>(
      Obf, WoT, d_out, nullptr, nullptr, boutF, MROWS, 1536, CC, flag);
}